// Round 7
// baseline (78.081 us; speedup 1.0000x reference)
//
#include <hip/hip_runtime.h>

#define NBINS 256
#define TPB 256
#define NCOPY 4       // one copy per wave
#define CSTRIDE 264   // 256 bins + dummy slot(256) + pad; copies bank-rotate by 8

typedef float f32x4 __attribute__((ext_vector_type(4)));

__global__ void zero_out_kernel(float* __restrict__ out) {
    out[threadIdx.x] = 0.0f;
}

__global__ __launch_bounds__(TPB) void hist_kernel(const float* __restrict__ x,
                                                   float* __restrict__ out,
                                                   int n) {
    __shared__ int lh[NCOPY * CSTRIDE];   // 4224 B
    const int tid = threadIdx.x;
    int* __restrict__ myh = &lh[(tid >> 6) * CSTRIDE];

    for (int i = tid; i < NCOPY * CSTRIDE; i += TPB)
        lh[i] = 0;
    __syncthreads();

    const int gid    = blockIdx.x * TPB + tid;
    const int stride = gridDim.x * TPB;     // in float4 units
    const int n4     = n >> 2;
    const f32x4* __restrict__ x4 = (const f32x4*)x;

    // Branchless bin math, bit-identical to reference:
    //   width = 8/256 = 0.03125 exact pow2 => floor((x-lo)/width) == trunc((x+4)*32)
    //   for in-range x; x==4 -> 256 -> clamp 255; NaN/out-of-range -> dummy slot
    //   256 (never flushed). Single range check |f|<=4 (abs is a free VOP3
    //   modifier; NaN fails). v_cvt_u32_f32 clamps negatives to 0 - masked by ok.
#define PROC(f) {                                        \
        float _t = ((f) + 4.0f) * 32.0f;                 \
        unsigned _u = (unsigned)_t;                      \
        _u = _u > 255u ? 255u : _u;                      \
        bool _ok = __builtin_fabsf(f) <= 4.0f;           \
        int _b = _ok ? (int)_u : 256;                    \
        atomicAdd(&myh[_b], 1);                          \
    }
#define PROC16(a, b, c, d) {                             \
        PROC(a.x) PROC(a.y) PROC(a.z) PROC(a.w)          \
        PROC(b.x) PROC(b.y) PROC(b.z) PROC(b.w)          \
        PROC(c.x) PROC(c.y) PROC(c.z) PROC(c.w)          \
        PROC(d.x) PROC(d.y) PROC(d.z) PROC(d.w)          \
    }

    // Each full iteration consumes 4 float4s/thread at [i, i+s, i+2s, i+3s],
    // advancing 4*stride. iters is wave-uniform (8 for the canonical shape).
    const int iters = n4 / (4 * stride);

    if (iters > 0) {
        // Phase-stagger: wave w starts at iteration p = w % iters and wraps.
        // Atomics are commutative -> any iteration order gives the same hist.
        // This decorrelates DS-burst vs load-burst phases across the 32
        // waves/CU so the LDS pipe and the HBM stream overlap.
        const int wave_gid = (blockIdx.x << 2) | (tid >> 6);
        const int p = wave_gid % iters;

        int t = p;
        int i = gid + t * 4 * stride;
        f32x4 a = __builtin_nontemporal_load(&x4[i]);
        f32x4 b = __builtin_nontemporal_load(&x4[i + stride]);
        f32x4 c = __builtin_nontemporal_load(&x4[i + 2 * stride]);
        f32x4 d = __builtin_nontemporal_load(&x4[i + 3 * stride]);
        for (int k = 1; k < iters; ++k) {
            int tn = t + 1;
            tn = (tn == iters) ? 0 : tn;        // wave-uniform wrap
            const int ni = gid + tn * 4 * stride;
            f32x4 na = __builtin_nontemporal_load(&x4[ni]);
            f32x4 nb = __builtin_nontemporal_load(&x4[ni + stride]);
            f32x4 nc = __builtin_nontemporal_load(&x4[ni + 2 * stride]);
            f32x4 nd = __builtin_nontemporal_load(&x4[ni + 3 * stride]);
            PROC16(a, b, c, d)
            a = na; b = nb; c = nc; d = nd;
            t = tn;
        }
        PROC16(a, b, c, d)
    }

    // leftover float4s beyond the uniform region (none for the canonical shape)
    for (int i = iters * 4 * stride + gid; i < n4; i += stride) {
        f32x4 a = __builtin_nontemporal_load(&x4[i]);
        PROC(a.x) PROC(a.y) PROC(a.z) PROC(a.w)
    }
    // scalar tail (n % 4 != 0 - not hit for N=64M)
    for (int j = (n4 << 2) + gid; j < n; j += stride) {
        float f = x[j];
        PROC(f)
    }
#undef PROC16
#undef PROC

    __syncthreads();

    // flush: bin `tid` summed across the 4 wave copies (consecutive-int reads,
    // conflict-free); one float atomic per bin per block. Counts are
    // integer-valued < 2^24 -> float adds exact & order-independent.
    int s = lh[0 * CSTRIDE + tid] + lh[1 * CSTRIDE + tid] +
            lh[2 * CSTRIDE + tid] + lh[3 * CSTRIDE + tid];
    if (s)
        atomicAdd(&out[tid], (float)s);
}

extern "C" void kernel_launch(void* const* d_in, const int* in_sizes, int n_in,
                              void* d_out, int out_size, void* d_ws, size_t ws_size,
                              hipStream_t stream) {
    const float* x = (const float*)d_in[0];
    float* out = (float*)d_out;
    const int n = in_sizes[0];

    // d_out is poisoned before timing and not re-zeroed between replays:
    // zero it ourselves every call (stream-ordered before hist).
    zero_out_kernel<<<1, NBINS, 0, stream>>>(out);

    int n4 = n >> 2;
    long long want = ((long long)n4 + (long long)TPB * 4 - 1) / ((long long)TPB * 4);
    int blocks = (int)(want < 1 ? 1 : (want > 2048 ? 2048 : want));
    hist_kernel<<<blocks, TPB, 0, stream>>>(x, out, n);
}

// Round 8
// 77.920 us; speedup vs baseline: 1.0021x; 1.0021x over previous
//
#include <hip/hip_runtime.h>

#define NBINS 256
#define TPB 256
#define NROWS 257              // 256 bins + dummy row (bin 256)
#define LDS_DW (NROWS * 32)    // counter(bin b, pair p) at dword b*32+p

typedef float f32x4 __attribute__((ext_vector_type(4)));

__global__ void zero_out_kernel(float* __restrict__ out) {
    out[threadIdx.x] = 0.0f;
}

__global__ __launch_bounds__(TPB) void hist_kernel(const float* __restrict__ x,
                                                   float* __restrict__ out,
                                                   int n) {
    // Bank-uniform layout: lane's atomic always hits bank (tid&31), regardless
    // of bin -> every ds_atomic wave-instr is a deterministic 2-way bank access
    // (free per m136), never a random Poisson max-load. Lanes l and l+32 (and
    // the other 3 waves' same-p lanes) share counters; that's only a short
    // same-address chain when bins coincide.
    __shared__ int lh[LDS_DW];   // 32896 B -> 4 blocks/CU, 16 waves/CU
    const int tid = threadIdx.x;
    int* __restrict__ myh = &lh[tid & 31];

    for (int i = tid; i < LDS_DW; i += TPB)
        lh[i] = 0;
    __syncthreads();

    const int gid    = blockIdx.x * TPB + tid;
    const int stride = gridDim.x * TPB;     // in float4 units
    const int n4     = n >> 2;
    const f32x4* __restrict__ x4 = (const f32x4*)x;

    // Branchless bin math, bit-identical to reference:
    //   width = 8/256 = 0.03125 exact pow2 => floor((x-lo)/width) == trunc((x+4)*32)
    //   for in-range x; x==4 -> 256 -> clamp 255; NaN/out-of-range -> dummy row
    //   256 (never flushed). Single range check |f|<=4 (abs modifier; NaN fails).
    //   (f+4)*32 shape is not fma-contractible.
#define PROC(f) {                                        \
        float _t = ((f) + 4.0f) * 32.0f;                 \
        unsigned _u = (unsigned)_t;                      \
        _u = _u > 255u ? 255u : _u;                      \
        bool _ok = __builtin_fabsf(f) <= 4.0f;           \
        int _b = _ok ? (int)_u : 256;                    \
        atomicAdd(&myh[_b << 5], 1);                     \
    }
#define PROC16(a, b, c, d) {                             \
        PROC(a.x) PROC(a.y) PROC(a.z) PROC(a.w)          \
        PROC(b.x) PROC(b.y) PROC(b.z) PROC(b.w)          \
        PROC(c.x) PROC(c.y) PROC(c.z) PROC(c.w)          \
        PROC(d.x) PROC(d.y) PROC(d.z) PROC(d.w)          \
    }

    const int iters = n4 / (4 * stride);   // wave-uniform (8 for canonical shape)

    // Depth-2 software pipeline: next iteration's 4 loads issued before
    // processing the current 4 float4s.
    if (iters > 0) {
        int i = gid;
        f32x4 a = __builtin_nontemporal_load(&x4[i]);
        f32x4 b = __builtin_nontemporal_load(&x4[i + stride]);
        f32x4 c = __builtin_nontemporal_load(&x4[i + 2 * stride]);
        f32x4 d = __builtin_nontemporal_load(&x4[i + 3 * stride]);
        for (int t = 1; t < iters; ++t) {
            const int ni = i + 4 * stride;
            f32x4 na = __builtin_nontemporal_load(&x4[ni]);
            f32x4 nb = __builtin_nontemporal_load(&x4[ni + stride]);
            f32x4 nc = __builtin_nontemporal_load(&x4[ni + 2 * stride]);
            f32x4 nd = __builtin_nontemporal_load(&x4[ni + 3 * stride]);
            PROC16(a, b, c, d)
            a = na; b = nb; c = nc; d = nd;
            i = ni;
        }
        PROC16(a, b, c, d)
    }

    for (int i = iters * 4 * stride + gid; i < n4; i += stride) {
        f32x4 a = __builtin_nontemporal_load(&x4[i]);
        PROC(a.x) PROC(a.y) PROC(a.z) PROC(a.w)
    }
    for (int j = (n4 << 2) + gid; j < n; j += stride) {
        float f = x[j];
        PROC(f)
    }
#undef PROC16
#undef PROC

    __syncthreads();

    // Flush: thread tid sums row tid (32 dwords = 8 int4s), int4-rotated by
    // tid&7 to spread lanes across column groups (once per block, cheap).
    const int4* row = (const int4*)&lh[tid * 32];
    int s = 0;
    #pragma unroll
    for (int k = 0; k < 8; ++k) {
        int4 v = row[(k + (tid & 7)) & 7];
        s += v.x + v.y + v.z + v.w;
    }
    if (s)
        atomicAdd(&out[tid], (float)s);   // integer-valued < 2^24: exact
}

extern "C" void kernel_launch(void* const* d_in, const int* in_sizes, int n_in,
                              void* d_out, int out_size, void* d_ws, size_t ws_size,
                              hipStream_t stream) {
    const float* x = (const float*)d_in[0];
    float* out = (float*)d_out;
    const int n = in_sizes[0];

    // d_out is poisoned before timing and not re-zeroed between replays:
    // zero it ourselves every call (stream-ordered before hist).
    zero_out_kernel<<<1, NBINS, 0, stream>>>(out);

    int n4 = n >> 2;
    long long want = ((long long)n4 + (long long)TPB * 4 - 1) / ((long long)TPB * 4);
    int blocks = (int)(want < 1 ? 1 : (want > 2048 ? 2048 : want));
    hist_kernel<<<blocks, TPB, 0, stream>>>(x, out, n);
}